// Round 4
// baseline (236.158 us; speedup 1.0000x reference)
//
#include <hip/hip_runtime.h>
#include <math.h>

#define B 16
#define D 8
#define FDIM 2
#define N 512
#define E 10          // D + FDIM
#define NP36 36       // pairs a<=d
#define GJW (2*E)     // augmented width for Gauss-Jordan
#define NT 4          // i-tiles per (pair,b)
#define TIL 128       // i-tile size
#define TSTR 12       // padded t-row stride (16B-aligned rows)
#define NQ (NP36*B*NT)   // 2304 k_q blocks
#define LOG2E 1.44269504088896340736f

// ---- workspace layout (float offsets) ----
#define OFF_MUD  0        // B*D        = 128
#define OFF_V    128      // B*D*E      = 1280
#define OFF_EDDP 1408     // NP36*B*NT  = 2304
#define OFF_TRP  3712     // D*B*NT     = 512
// total 4224 floats

__device__ __forceinline__ void decode_pair(int p36, int* pa, int* pd) {
  int a = 0, rem = p36;
  while (rem >= D - a) { rem -= (D - a); a++; }
  *pa = a; *pd = a + rem;
}

__device__ __forceinline__ float wave_reduce(float v) {
#pragma unroll
  for (int off = 32; off > 0; off >>= 1) v += __shfl_down(v, off);
  return v;
}

// Cooperative Gauss-Jordan w/ partial pivoting on augmented E x GJW system in
// LDS. 256 threads (row-ops strided; swap step by wave-0 lanes in lockstep).
// On exit: right half = left^{-1} * original-right, *s_logdet = log|det(left)|.
__device__ __forceinline__ void gj(float (*M)[GJW], float* pivrow, float* colfac,
                                   int* s_piv, float* s_logdet, int tid) {
  if (tid == 0) *s_logdet = 0.0f;
  __syncthreads();
  for (int k = 0; k < E; k++) {
    if (tid == 0) {
      int pr = k; float best = fabsf(M[k][k]);
      for (int r = k + 1; r < E; r++) {
        float v = fabsf(M[r][k]);
        if (v > best) { best = v; pr = r; }
      }
      *s_piv = pr;
      *s_logdet += logf(fabsf(M[pr][k]));
    }
    __syncthreads();
    int pr = *s_piv;
    if (tid < GJW) {               // wave-0 lanes: loads precede stores in lockstep
      int c = tid;
      float piv = M[pr][k];
      float tmp = M[pr][c];
      float tk  = M[k][c];
      float pw  = tmp / piv;
      pivrow[c] = pw;
      M[pr][c] = tk;               // if pr==k, second store wins (correct)
      M[k][c]  = pw;
    }
    __syncthreads();
    if (tid < E) colfac[tid] = M[tid][k];
    __syncthreads();
    for (int idx = tid; idx < E * GJW; idx += 256) {
      int r = idx / GJW, c = idx % GJW;
      if (r != k) M[r][c] -= colfac[r] * pivrow[c];
    }
    __syncthreads();
  }
}

// ---------------------------------------------------------------------------
// Fat kernel: blocks [0,NQ) do the Q contraction for (pair,b,tile);
// blocks [NQ, NQ+B*D) compute mu_delta + V for (b,d). All from raw inputs.
__global__ __launch_bounds__(256, 2) void k_main(
    const float* __restrict__ obs_mean, const float* __restrict__ obs_var,
    const float* __restrict__ action_mean, const float* __restrict__ action_var,
    const float* __restrict__ cross_cov, const float* __restrict__ X,
    const float* __restrict__ ell, const float* __restrict__ alpha_sq,
    const float* __restrict__ beta, const float* __restrict__ invK,
    float* __restrict__ ws) {
  __shared__ float M[E][GJW];
  __shared__ float pivrow[GJW];
  __shared__ float colfac[E];
  __shared__ int   s_piv;
  __shared__ float s_logdet;
  __shared__ float sMu[E], sSig[E * E], siLa[E], siLd[E];
  __shared__ float sW[E * E];
  __shared__ float snu[TIL * E];
  __shared__ float sT[TIL * TSTR];
  __shared__ float sca[TIL], sba[TIL];
  __shared__ float scb[N];
  __shared__ float wred[4][11];
  __shared__ float wsh[E];
  __shared__ float redw[8];

  int tid = threadIdx.x;
  int bx = blockIdx.x;

  if (bx >= NQ) {
    // ================= k_A path: mu_delta[b,d], V[b,d,:] =================
    int bd = bx - NQ;
    int b = bd / D, d = bd % D;
    if (tid < E) {
      sMu[tid] = (tid < D) ? obs_mean[b * D + tid] : action_mean[b * FDIM + tid - D];
      float l = ell[d * E + tid]; siLd[tid] = 1.0f / (l * l);
    }
    for (int idx = tid; idx < E * E; idx += 256) {
      int e = idx / E, f = idx % E;
      float v;
      if (e < D && f < D)      v = obs_var[(b * D + e) * D + f];
      else if (e < D)          v = cross_cov[(b * D + e) * FDIM + (f - D)];
      else if (f < D)          v = cross_cov[(b * D + f) * FDIM + (e - D)];
      else                     v = action_var[(b * FDIM + (e - D)) * FDIM + (f - D)];
      sSig[idx] = v;
    }
    __syncthreads();
    for (int idx = tid; idx < E * GJW; idx += 256) {
      int r = idx / GJW, c = idx % GJW;
      float v;
      if (c < E) {
        v = sSig[r * E + c];
        if (r == c) { float l = ell[d * E + r]; v += l * l; }
      } else {
        v = (c - E == r) ? 1.0f : 0.0f;
      }
      M[r][c] = v;
    }
    gj(M, pivrow, colfac, &s_piv, &s_logdet, tid);  // M[r][E+c] = Ainv
    float lda = s_logdet;
    float a2 = alpha_sq[d];
    float logdetLam = 0.0f;
#pragma unroll
    for (int e = 0; e < E; e++) { float l = ell[d * E + e]; logdetLam += logf(l * l); }
    float c0 = 0.5f * (logdetLam - lda);
    float acc_mu = 0.0f, acc_w[E];
#pragma unroll
    for (int e = 0; e < E; e++) acc_w[e] = 0.0f;
    for (int n = tid; n < N; n += 256) {
      float x[E];
#pragma unroll
      for (int e = 0; e < E; e++) x[e] = X[n * E + e] - sMu[e];
      float quad = 0.0f;
#pragma unroll
      for (int e = 0; e < E; e++) {
        float te = 0.0f;
#pragma unroll
        for (int f = 0; f < E; f++) te += M[e][E + f] * x[f];
        quad += x[e] * te;
      }
      float qval = a2 * __expf(c0 - 0.5f * quad);
      float bq = beta[d * N + n] * qval;
      acc_mu += bq;
#pragma unroll
      for (int e = 0; e < E; e++) acc_w[e] += bq * x[e];
    }
    int wid = tid >> 6, lane = tid & 63;
    float r = wave_reduce(acc_mu);
    if (lane == 0) wred[wid][0] = r;
#pragma unroll
    for (int e = 0; e < E; e++) {
      r = wave_reduce(acc_w[e]);
      if (lane == 0) wred[wid][e + 1] = r;
    }
    __syncthreads();
    if (tid < 11) {
      float s = wred[0][tid] + wred[1][tid] + wred[2][tid] + wred[3][tid];
      if (tid == 0) ws[OFF_MUD + b * D + d] = s;
      else wsh[tid - 1] = s;
    }
    __syncthreads();
    if (tid == 0) {
      float u[E];
#pragma unroll
      for (int f = 0; f < E; f++) {
        float s = 0.0f;
#pragma unroll
        for (int g = 0; g < E; g++) s += M[f][E + g] * wsh[g];
        u[f] = s;
      }
#pragma unroll
      for (int e = 0; e < E; e++) {
        float s = 0.0f;
#pragma unroll
        for (int f = 0; f < E; f++) s += sSig[e * E + f] * u[f];
        ws[OFF_V + (b * D + d) * E + e] = s;
      }
    }
    return;
  }

  // ================= k_q path: EDD / trace partials =================
  int tile = bx & (NT - 1);
  int rest = bx >> 2;
  int b = rest & (B - 1);
  int p36 = rest >> 4;
  int a, d;
  decode_pair(p36, &a, &d);
  bool diag = (a == d);
  int i0 = tile * TIL;

  // phase 0: mu, Sigma, inverse length-scales
  if (tid < E) {
    sMu[tid] = (tid < D) ? obs_mean[b * D + tid] : action_mean[b * FDIM + tid - D];
    float la = ell[a * E + tid]; siLa[tid] = 1.0f / (la * la);
    float ld = ell[d * E + tid]; siLd[tid] = 1.0f / (ld * ld);
  }
  for (int idx = tid; idx < E * E; idx += 256) {
    int e = idx / E, f = idx % E;
    float v;
    if (e < D && f < D)      v = obs_var[(b * D + e) * D + f];
    else if (e < D)          v = cross_cov[(b * D + e) * FDIM + (f - D)];
    else if (f < D)          v = cross_cov[(b * D + f) * FDIM + (e - D)];
    else                     v = action_var[(b * FDIM + (e - D)) * FDIM + (f - D)];
    sSig[idx] = v;
  }
  __syncthreads();

  // phase 1: assemble R|Sigma for GJ; stage nu i-tile; load per-thread j-frag
  for (int idx = tid; idx < E * GJW; idx += 256) {
    int r = idx / GJW, c = idx % GJW;
    float v;
    if (c < E) v = sSig[r * E + c] * (siLa[c] + siLd[c]) + ((r == c) ? 1.0f : 0.0f);
    else       v = sSig[r * E + (c - E)];
    M[r][c] = v;
  }
  for (int idx = tid; idx < TIL * E; idx += 256) {
    int e = idx % E;
    snu[idx] = X[i0 * E + idx] - sMu[e];
  }
  int jgrp = tid & 127;
  int ihalf = tid >> 7;
  int jbase = jgrp * 4;
  float xr[40];
  {
    const float4* xp = (const float4*)(X + (size_t)jbase * E);
#pragma unroll
    for (int q4 = 0; q4 < 10; q4++) {
      float4 v = xp[q4];
      xr[q4 * 4 + 0] = v.x; xr[q4 * 4 + 1] = v.y;
      xr[q4 * 4 + 2] = v.z; xr[q4 * 4 + 3] = v.w;
    }
  }
#pragma unroll
  for (int k = 0; k < 4; k++)
#pragma unroll
    for (int f = 0; f < E; f++) xr[k * 10 + f] -= sMu[f];
  float vb[4];
#pragma unroll
  for (int k = 0; k < 4; k++) vb[k] = beta[d * N + jbase + k];

  gj(M, pivrow, colfac, &s_piv, &s_logdet, tid);   // M[r][E+c] = S, s_logdet = logdetR
  float ldr = s_logdet;
  float lga = logf(alpha_sq[a]);
  float lgd = logf(alpha_sq[d]);

  // phase 3: sW (log2e-folded), sca (i-tile), scb (all j), sba
  for (int idx = tid; idx < E * E; idx += 256) {
    int e = idx / E, f = idx % E;
    sW[idx] = LOG2E * M[e][E + f] * siLa[e] * siLd[f];
  }
  if (tid < TIL) {
    int il = tid;
    float pa[E]; float s2 = 0.0f;
#pragma unroll
    for (int e = 0; e < E; e++) {
      float x = snu[il * E + e];
      pa[e] = x * siLa[e];
      s2 += x * pa[e];
    }
    float da = 0.0f;
#pragma unroll
    for (int e = 0; e < E; e++) {
      float te = 0.0f;
#pragma unroll
      for (int f = 0; f < E; f++) te += M[e][E + f] * pa[f];
      da += pa[e] * te;
    }
    sca[il] = LOG2E * (lga - 0.5f * s2 + 0.5f * da - 0.5f * ldr);
    sba[il] = beta[a * N + i0 + il];
  }
  for (int j = tid; j < N; j += 256) {
    float x[E], pd[E]; float s2 = 0.0f;
#pragma unroll
    for (int e = 0; e < E; e++) {
      x[e] = X[j * E + e] - sMu[e];
      pd[e] = x[e] * siLd[e];
      s2 += x[e] * pd[e];
    }
    float db = 0.0f;
#pragma unroll
    for (int e = 0; e < E; e++) {
      float te = 0.0f;
#pragma unroll
      for (int f = 0; f < E; f++) te += M[e][E + f] * pd[f];
      db += pd[e] * te;
    }
    scb[j] = LOG2E * (lgd - 0.5f * s2 + 0.5f * db);
  }
  __syncthreads();

  // phase 4: t rows (already scaled by log2e via sW)
  for (int idx = tid; idx < TIL * E; idx += 256) {
    int il = idx / E, f = idx % E;
    float acc = 0.0f;
#pragma unroll
    for (int e = 0; e < E; e++) acc += snu[il * E + e] * sW[e * E + f];
    sT[il * TSTR + f] = acc;
  }
  float cbv[4];
#pragma unroll
  for (int k = 0; k < 4; k++) cbv[k] = scb[jbase + k];
  __syncthreads();

  // phase 5: main bilinear + exp2 loop
  const float* invKa = invK + (size_t)a * N * N;
  float acc_rows = 0.0f, acc_tr = 0.0f;
  int ibase = ihalf * 64;
#pragma unroll 2
  for (int ii = 0; ii < 32; ii++) {
    int il = ibase + ii * 2;
    const float4* tp = (const float4*)&sT[il * TSTR];
    float4 t0a = tp[0], t0b = tp[1], t0c = tp[2];
    float4 t1a = tp[3], t1b = tp[4], t1c = tp[5];
    float tr0[10] = {t0a.x, t0a.y, t0a.z, t0a.w, t0b.x, t0b.y, t0b.z, t0b.w, t0c.x, t0c.y};
    float tr1[10] = {t1a.x, t1a.y, t1a.z, t1a.w, t1b.x, t1b.y, t1b.z, t1b.w, t1c.x, t1c.y};
    float cai0 = sca[il], cai1 = sca[il + 1];
    float ba0 = sba[il], ba1 = sba[il + 1];
    float4 r0, r1;
    if (diag) {
      r0 = *(const float4*)(invKa + (size_t)(i0 + il) * N + jbase);
      r1 = *(const float4*)(invKa + (size_t)(i0 + il + 1) * N + jbase);
    }
#pragma unroll
    for (int k = 0; k < 4; k++) {
      float m0 = 0.0f, m1 = 0.0f;
#pragma unroll
      for (int f = 0; f < E; f++) {
        float x = xr[k * 10 + f];
        m0 += tr0[f] * x;
        m1 += tr1[f] * x;
      }
      float q0 = exp2f(cai0 + cbv[k] + m0);
      float q1 = exp2f(cai1 + cbv[k] + m1);
      acc_rows += vb[k] * (ba0 * q0 + ba1 * q1);
      if (diag) {
        acc_tr += ((const float*)&r0)[k] * q0 + ((const float*)&r1)[k] * q1;
      }
    }
  }

  // reductions (wave shuffle + one LDS step)
  {
    float rr = wave_reduce(acc_rows);
    int wid = tid >> 6, lane = tid & 63;
    if (lane == 0) redw[wid] = rr;
    if (diag) {
      float rt = wave_reduce(acc_tr);
      if (lane == 0) redw[4 + wid] = rt;
    }
    __syncthreads();
    if (tid == 0) {
      ws[OFF_EDDP + (p36 * B + b) * NT + tile] = redw[0] + redw[1] + redw[2] + redw[3];
      if (diag)
        ws[OFF_TRP + (a * B + b) * NT + tile] = redw[4] + redw[5] + redw[6] + redw[7];
    }
  }
}

// ---------------------------------------------------------------------------
// Final assembly (sums tile partials)
__global__ __launch_bounds__(64) void k_final(
    const float* __restrict__ obs_mean, const float* __restrict__ obs_var,
    const float* __restrict__ alpha_sq, const float* __restrict__ sigma_sq_eps,
    const float* __restrict__ ws, float* __restrict__ out) {
  int b = blockIdx.x;
  int tid = threadIdx.x;
  const float* mud = ws + OFF_MUD + b * D;
  if (tid < D) out[b * D + tid] = obs_mean[b * D + tid] + mud[tid];
  if (tid < D * D) {
    int i = tid / D, j = tid % D;
    int a = i < j ? i : j;
    int dd = i < j ? j : i;
    int p36 = a * D - a * (a - 1) / 2 + (dd - a);
    float edd = 0.0f;
#pragma unroll
    for (int tt = 0; tt < NT; tt++) edd += ws[OFF_EDDP + (p36 * B + b) * NT + tt];
    float sd = edd - mud[i] * mud[j];
    if (i == j) {
      float tr = 0.0f;
#pragma unroll
      for (int tt = 0; tt < NT; tt++) tr += ws[OFF_TRP + (i * B + b) * NT + tt];
      sd += alpha_sq[i] - tr + sigma_sq_eps[i];
    }
    const float* V = ws + OFF_V;
    float cxd = V[(b * D + j) * E + i];   // C_xd[b,i,j] = V[b,j,i]
    float cdx = V[(b * D + i) * E + j];   // C_xd[b,j,i] = V[b,i,j]
    out[B * D + b * D * D + tid] = obs_var[b * D * D + tid] + sd + cxd + cdx;
  }
}

// ---------------------------------------------------------------------------
extern "C" void kernel_launch(void* const* d_in, const int* in_sizes, int n_in,
                              void* d_out, int out_size, void* d_ws, size_t ws_size,
                              hipStream_t stream) {
  const float* obs_mean     = (const float*)d_in[0];
  const float* obs_var      = (const float*)d_in[1];
  const float* action_mean  = (const float*)d_in[2];
  const float* action_var   = (const float*)d_in[3];
  const float* cross_cov    = (const float*)d_in[4];
  const float* X_train      = (const float*)d_in[5];
  const float* ell          = (const float*)d_in[6];
  const float* alpha_sq     = (const float*)d_in[7];
  const float* sigma_sq_eps = (const float*)d_in[8];
  const float* beta         = (const float*)d_in[9];
  const float* inv_K        = (const float*)d_in[10];
  float* out = (float*)d_out;
  float* ws = (float*)d_ws;

  k_main<<<NQ + B * D, 256, 0, stream>>>(obs_mean, obs_var, action_mean,
                                         action_var, cross_cov, X_train, ell,
                                         alpha_sq, beta, inv_K, ws);
  k_final<<<B, 64, 0, stream>>>(obs_mean, obs_var, alpha_sq, sigma_sq_eps, ws, out);
}

// Round 5
// 192.042 us; speedup vs baseline: 1.2297x; 1.2297x over previous
//
#include <hip/hip_runtime.h>
#include <math.h>

#define B 16
#define D 8
#define FDIM 2
#define N 512
#define E 10          // D + FDIM
#define NP36 36       // pairs a<=d
#define GJW (2*E)     // augmented width for Gauss-Jordan
#define NT 4          // i-tiles per (pair,b)
#define TIL 128       // i-tile size
#define TSTR 12       // t-row stride: [t0..t9, ca_i, 1.0]
#define NQ (NP36*B*NT)     // 2304 k_q blocks
#define NPREP (NP36*B + B*D)  // 576 pair-blocks + 128 A-blocks
#define LOG2E 1.44269504088896340736f

// ---- workspace layout (float offsets) ----
#define OFF_MUD  0         // B*D          = 128
#define OFF_V    128       // B*D*E        = 1280
#define OFF_EDDP 1408      // NP36*B*NT    = 2304
#define OFF_TRP  3712      // D*B*NT       = 512
#define OFF_W    4224      // NP36*B*E*E   = 57600
#define OFF_CA   61824     // NP36*B*N     = 294912
#define OFF_CB   356736    // NP36*B*N     = 294912
// total 651648 floats = 2.6 MB

__device__ __forceinline__ void decode_pair(int p36, int* pa, int* pd) {
  int a = 0, rem = p36;
  while (rem >= D - a) { rem -= (D - a); a++; }
  *pa = a; *pd = a + rem;
}

__device__ __forceinline__ float wave_reduce(float v) {
#pragma unroll
  for (int off = 32; off > 0; off >>= 1) v += __shfl_down(v, off);
  return v;
}

// Cooperative Gauss-Jordan w/ partial pivoting on augmented E x GJW system in
// LDS (256 threads). On exit: right half = left^{-1} * original-right,
// *s_logdet = log|det(left)|.
__device__ __forceinline__ void gj(float (*M)[GJW], float* pivrow, float* colfac,
                                   int* s_piv, float* s_logdet, int tid) {
  if (tid == 0) *s_logdet = 0.0f;
  __syncthreads();
  for (int k = 0; k < E; k++) {
    if (tid == 0) {
      int pr = k; float best = fabsf(M[k][k]);
      for (int r = k + 1; r < E; r++) {
        float v = fabsf(M[r][k]);
        if (v > best) { best = v; pr = r; }
      }
      *s_piv = pr;
      *s_logdet += logf(fabsf(M[pr][k]));
    }
    __syncthreads();
    int pr = *s_piv;
    if (tid < GJW) {               // wave-0 lanes, loads precede stores in lockstep
      int c = tid;
      float piv = M[pr][k];
      float tmp = M[pr][c];
      float tk  = M[k][c];
      float pw  = tmp / piv;
      pivrow[c] = pw;
      M[pr][c] = tk;
      M[k][c]  = pw;
    }
    __syncthreads();
    if (tid < E) colfac[tid] = M[tid][k];
    __syncthreads();
    for (int idx = tid; idx < E * GJW; idx += 256) {
      int r = idx / GJW, c = idx % GJW;
      if (r != k) M[r][c] -= colfac[r] * pivrow[c];
    }
    __syncthreads();
  }
}

// ---------------------------------------------------------------------------
// k_prep: blocks [0, NP36*B): per-(pair,b) GJ -> W (log2e-scaled), CA, CB.
//         blocks [NP36*B, +B*D): mu_delta[b,d] and V[b,d,:].
__global__ __launch_bounds__(256) void k_prep(
    const float* __restrict__ obs_mean, const float* __restrict__ obs_var,
    const float* __restrict__ action_mean, const float* __restrict__ action_var,
    const float* __restrict__ cross_cov, const float* __restrict__ X,
    const float* __restrict__ ell, const float* __restrict__ alpha_sq,
    const float* __restrict__ beta, float* __restrict__ ws) {
  __shared__ float M[E][GJW];
  __shared__ float pivrow[GJW];
  __shared__ float colfac[E];
  __shared__ int   s_piv;
  __shared__ float s_logdet;
  __shared__ float sMu[E], sSig[E * E], siLa[E], siLd[E];
  __shared__ float wred[4][11];
  __shared__ float wsh[E];

  int tid = threadIdx.x;
  int bx = blockIdx.x;

  if (bx >= NP36 * B) {
    // ===== A-path: mu_delta[b,d], V[b,d,:] =====
    int bd = bx - NP36 * B;
    int b = bd / D, d = bd % D;
    if (tid < E) {
      sMu[tid] = (tid < D) ? obs_mean[b * D + tid] : action_mean[b * FDIM + tid - D];
    }
    for (int idx = tid; idx < E * E; idx += 256) {
      int e = idx / E, f = idx % E;
      float v;
      if (e < D && f < D)      v = obs_var[(b * D + e) * D + f];
      else if (e < D)          v = cross_cov[(b * D + e) * FDIM + (f - D)];
      else if (f < D)          v = cross_cov[(b * D + f) * FDIM + (e - D)];
      else                     v = action_var[(b * FDIM + (e - D)) * FDIM + (f - D)];
      sSig[idx] = v;
    }
    __syncthreads();
    for (int idx = tid; idx < E * GJW; idx += 256) {
      int r = idx / GJW, c = idx % GJW;
      float v;
      if (c < E) {
        v = sSig[r * E + c];
        if (r == c) { float l = ell[d * E + r]; v += l * l; }
      } else {
        v = (c - E == r) ? 1.0f : 0.0f;
      }
      M[r][c] = v;
    }
    gj(M, pivrow, colfac, &s_piv, &s_logdet, tid);  // M[r][E+c] = Ainv
    float lda = s_logdet;
    float a2 = alpha_sq[d];
    float logdetLam = 0.0f;
#pragma unroll
    for (int e = 0; e < E; e++) { float l = ell[d * E + e]; logdetLam += logf(l * l); }
    float c0 = 0.5f * (logdetLam - lda);
    float acc_mu = 0.0f, acc_w[E];
#pragma unroll
    for (int e = 0; e < E; e++) acc_w[e] = 0.0f;
    for (int n = tid; n < N; n += 256) {
      float x[E];
#pragma unroll
      for (int e = 0; e < E; e++) x[e] = X[n * E + e] - sMu[e];
      float quad = 0.0f;
#pragma unroll
      for (int e = 0; e < E; e++) {
        float te = 0.0f;
#pragma unroll
        for (int f = 0; f < E; f++) te += M[e][E + f] * x[f];
        quad += x[e] * te;
      }
      float qval = a2 * __expf(c0 - 0.5f * quad);
      float bq = beta[d * N + n] * qval;
      acc_mu += bq;
#pragma unroll
      for (int e = 0; e < E; e++) acc_w[e] += bq * x[e];
    }
    int wid = tid >> 6, lane = tid & 63;
    float r = wave_reduce(acc_mu);
    if (lane == 0) wred[wid][0] = r;
#pragma unroll
    for (int e = 0; e < E; e++) {
      r = wave_reduce(acc_w[e]);
      if (lane == 0) wred[wid][e + 1] = r;
    }
    __syncthreads();
    if (tid < 11) {
      float s = wred[0][tid] + wred[1][tid] + wred[2][tid] + wred[3][tid];
      if (tid == 0) ws[OFF_MUD + b * D + d] = s;
      else wsh[tid - 1] = s;
    }
    __syncthreads();
    if (tid == 0) {
      float u[E];
#pragma unroll
      for (int f = 0; f < E; f++) {
        float s = 0.0f;
#pragma unroll
        for (int g = 0; g < E; g++) s += M[f][E + g] * wsh[g];
        u[f] = s;
      }
#pragma unroll
      for (int e = 0; e < E; e++) {
        float s = 0.0f;
#pragma unroll
        for (int f = 0; f < E; f++) s += sSig[e * E + f] * u[f];
        ws[OFF_V + (b * D + d) * E + e] = s;
      }
    }
    return;
  }

  // ===== pair path: W, CA, CB for (p36, b) =====
  int p36 = bx / B, b = bx % B;
  int a, d;
  decode_pair(p36, &a, &d);
  int pb = p36 * B + b;
  if (tid < E) {
    sMu[tid] = (tid < D) ? obs_mean[b * D + tid] : action_mean[b * FDIM + tid - D];
    float la = ell[a * E + tid]; siLa[tid] = 1.0f / (la * la);
    float ld = ell[d * E + tid]; siLd[tid] = 1.0f / (ld * ld);
  }
  for (int idx = tid; idx < E * E; idx += 256) {
    int e = idx / E, f = idx % E;
    float v;
    if (e < D && f < D)      v = obs_var[(b * D + e) * D + f];
    else if (e < D)          v = cross_cov[(b * D + e) * FDIM + (f - D)];
    else if (f < D)          v = cross_cov[(b * D + f) * FDIM + (e - D)];
    else                     v = action_var[(b * FDIM + (e - D)) * FDIM + (f - D)];
    sSig[idx] = v;
  }
  __syncthreads();
  for (int idx = tid; idx < E * GJW; idx += 256) {
    int r = idx / GJW, c = idx % GJW;
    float v;
    if (c < E) v = sSig[r * E + c] * (siLa[c] + siLd[c]) + ((r == c) ? 1.0f : 0.0f);
    else       v = sSig[r * E + (c - E)];
    M[r][c] = v;
  }
  gj(M, pivrow, colfac, &s_piv, &s_logdet, tid);   // M[r][E+c] = S
  float ldr = s_logdet;
  float lga = logf(alpha_sq[a]);
  float lgd = logf(alpha_sq[d]);
  for (int idx = tid; idx < E * E; idx += 256) {
    int e = idx / E, f = idx % E;
    ws[OFF_W + pb * (E * E) + idx] = LOG2E * M[e][E + f] * siLa[e] * siLd[f];
  }
  for (int n = tid; n < N; n += 256) {
    float x[E], pa[E], pd[E];
    float s2a = 0.0f, s2b = 0.0f;
#pragma unroll
    for (int e = 0; e < E; e++) {
      float xe = X[n * E + e] - sMu[e];
      x[e] = xe;
      pa[e] = xe * siLa[e];
      pd[e] = xe * siLd[e];
      s2a += xe * pa[e];
      s2b += xe * pd[e];
    }
    float da = 0.0f, db = 0.0f;
#pragma unroll
    for (int e = 0; e < E; e++) {
      float ta = 0.0f, td = 0.0f;
#pragma unroll
      for (int f = 0; f < E; f++) {
        float s = M[e][E + f];
        ta += s * pa[f];
        td += s * pd[f];
      }
      da += pa[e] * ta;
      db += pd[e] * td;
    }
    ws[OFF_CA + pb * N + n] = LOG2E * (lga - 0.5f * s2a + 0.5f * da - 0.5f * ldr);
    ws[OFF_CB + pb * N + n] = LOG2E * (lgd - 0.5f * s2b + 0.5f * db);
  }
}

// ---------------------------------------------------------------------------
// k_q: Q contraction per (pair, b, i-tile). 256 threads.
// Thread: Jt=4 consecutive j in registers (augmented 12-wide), It=2 rows/step.
__global__ __launch_bounds__(256) void k_q(
    const float* __restrict__ obs_mean, const float* __restrict__ action_mean,
    const float* __restrict__ X, const float* __restrict__ beta,
    const float* __restrict__ invK, float* __restrict__ ws) {
  __shared__ float sT[TIL * TSTR];   // rows: [t0..t9, ca_i, 1.0]
  __shared__ float snu[TIL * E];
  __shared__ float sW[E * E];
  __shared__ float sMu[E];
  __shared__ float sba[TIL];
  __shared__ float redw[8];

  int tid = threadIdx.x;
  int bx = blockIdx.x;
  int tile = bx & (NT - 1);
  int rest = bx >> 2;
  int b = rest & (B - 1);
  int p36 = rest >> 4;
  int a, d;
  decode_pair(p36, &a, &d);
  int pb = p36 * B + b;
  bool diag = (a == d);
  int i0 = tile * TIL;

  // phase 1: small shared fills
  if (tid < E) {
    sMu[tid] = (tid < D) ? obs_mean[b * D + tid] : action_mean[b * FDIM + tid - D];
  }
  if (tid < E * E) sW[tid] = ws[OFF_W + pb * (E * E) + tid];
  if (tid < TIL) sba[tid] = beta[a * N + i0 + tid];
  __syncthreads();

  // phase 2: snu i-tile (coalesced) + per-thread j fragment (augmented)
  for (int idx = tid; idx < TIL * E; idx += 256) {
    snu[idx] = X[i0 * E + idx] - sMu[idx % E];
  }
  int jgrp = tid & 127;
  int ihalf = tid >> 7;
  int jbase = jgrp * 4;
  float4 xa[4], xb[4], xc[4];
  {
    const float4* xp = (const float4*)(X + (size_t)jbase * E);
    float4 v0 = xp[0], v1 = xp[1], v2 = xp[2], v3 = xp[3], v4 = xp[4];
    float4 v5 = xp[5], v6 = xp[6], v7 = xp[7], v8 = xp[8], v9 = xp[9];
    float4 cbq = *(const float4*)(ws + OFF_CB + (size_t)pb * N + jbase);
    float m0 = sMu[0], m1 = sMu[1], m2 = sMu[2], m3 = sMu[3], m4 = sMu[4];
    float m5 = sMu[5], m6 = sMu[6], m7 = sMu[7], m8 = sMu[8], m9 = sMu[9];
    // j = jbase+0 : elems v0.x..v2.y
    xa[0] = make_float4(v0.x - m0, v0.y - m1, v0.z - m2, v0.w - m3);
    xb[0] = make_float4(v1.x - m4, v1.y - m5, v1.z - m6, v1.w - m7);
    xc[0] = make_float4(v2.x - m8, v2.y - m9, 1.0f, cbq.x);
    // j+1 : v2.z..v4.w
    xa[1] = make_float4(v2.z - m0, v2.w - m1, v3.x - m2, v3.y - m3);
    xb[1] = make_float4(v3.z - m4, v3.w - m5, v4.x - m6, v4.y - m7);
    xc[1] = make_float4(v4.z - m8, v4.w - m9, 1.0f, cbq.y);
    // j+2 : v5.x..v7.y
    xa[2] = make_float4(v5.x - m0, v5.y - m1, v5.z - m2, v5.w - m3);
    xb[2] = make_float4(v6.x - m4, v6.y - m5, v6.z - m6, v6.w - m7);
    xc[2] = make_float4(v7.x - m8, v7.y - m9, 1.0f, cbq.z);
    // j+3 : v7.z..v9.w
    xa[3] = make_float4(v7.z - m0, v7.w - m1, v8.x - m2, v8.y - m3);
    xb[3] = make_float4(v8.z - m4, v8.w - m5, v9.x - m6, v9.y - m7);
    xc[3] = make_float4(v9.z - m8, v9.w - m9, 1.0f, cbq.w);
  }
  float4 vbq = *(const float4*)(beta + (size_t)d * N + jbase);
  float vba[4] = {vbq.x, vbq.y, vbq.z, vbq.w};
  __syncthreads();

  // phase 3: t rows (scaled by log2e via sW), augmented with ca / 1.0
  for (int idx = tid; idx < TIL * E; idx += 256) {
    int il = idx / E, f = idx % E;
    float acc = 0.0f;
#pragma unroll
    for (int e = 0; e < E; e++) acc += snu[il * E + e] * sW[e * E + f];
    sT[il * TSTR + f] = acc;
  }
  if (tid < TIL) {
    sT[tid * TSTR + 10] = ws[OFF_CA + (size_t)pb * N + i0 + tid];
    sT[tid * TSTR + 11] = 1.0f;
  }
  __syncthreads();

  // phase 4: main augmented-dot + exp2 loop
  const float* invKa = invK + (size_t)a * N * N;
  float acc_rows = 0.0f, acc_tr = 0.0f;
  int ibase = ihalf * 64;
#pragma unroll 2
  for (int ii = 0; ii < 32; ii++) {
    int il = ibase + ii * 2;
    const float4* tp = (const float4*)&sT[il * TSTR];
    float4 t0a = tp[0], t0b = tp[1], t0c = tp[2];
    float4 t1a = tp[3], t1b = tp[4], t1c = tp[5];
    float ba0 = sba[il], ba1 = sba[il + 1];
    float r0a[4], r1a[4];
    if (diag) {
      float4 r0 = *(const float4*)(invKa + (size_t)(i0 + il) * N + jbase);
      float4 r1 = *(const float4*)(invKa + (size_t)(i0 + il + 1) * N + jbase);
      r0a[0] = r0.x; r0a[1] = r0.y; r0a[2] = r0.z; r0a[3] = r0.w;
      r1a[0] = r1.x; r1a[1] = r1.y; r1a[2] = r1.z; r1a[3] = r1.w;
    }
#pragma unroll
    for (int k = 0; k < 4; k++) {
      float m0 = t0a.x * xa[k].x;
      m0 = fmaf(t0a.y, xa[k].y, m0);
      m0 = fmaf(t0a.z, xa[k].z, m0);
      m0 = fmaf(t0a.w, xa[k].w, m0);
      m0 = fmaf(t0b.x, xb[k].x, m0);
      m0 = fmaf(t0b.y, xb[k].y, m0);
      m0 = fmaf(t0b.z, xb[k].z, m0);
      m0 = fmaf(t0b.w, xb[k].w, m0);
      m0 = fmaf(t0c.x, xc[k].x, m0);
      m0 = fmaf(t0c.y, xc[k].y, m0);
      m0 = fmaf(t0c.z, xc[k].z, m0);
      m0 = fmaf(t0c.w, xc[k].w, m0);
      float m1 = t1a.x * xa[k].x;
      m1 = fmaf(t1a.y, xa[k].y, m1);
      m1 = fmaf(t1a.z, xa[k].z, m1);
      m1 = fmaf(t1a.w, xa[k].w, m1);
      m1 = fmaf(t1b.x, xb[k].x, m1);
      m1 = fmaf(t1b.y, xb[k].y, m1);
      m1 = fmaf(t1b.z, xb[k].z, m1);
      m1 = fmaf(t1b.w, xb[k].w, m1);
      m1 = fmaf(t1c.x, xc[k].x, m1);
      m1 = fmaf(t1c.y, xc[k].y, m1);
      m1 = fmaf(t1c.z, xc[k].z, m1);
      m1 = fmaf(t1c.w, xc[k].w, m1);
      float q0 = exp2f(m0);
      float q1 = exp2f(m1);
      float tsum = fmaf(ba1, q1, ba0 * q0);
      acc_rows = fmaf(vba[k], tsum, acc_rows);
      if (diag) {
        acc_tr = fmaf(r0a[k], q0, acc_tr);
        acc_tr = fmaf(r1a[k], q1, acc_tr);
      }
    }
  }

  // reductions (wave shuffle + one LDS step)
  {
    float rr = wave_reduce(acc_rows);
    int wid = tid >> 6, lane = tid & 63;
    if (lane == 0) redw[wid] = rr;
    if (diag) {
      float rt = wave_reduce(acc_tr);
      if (lane == 0) redw[4 + wid] = rt;
    }
    __syncthreads();
    if (tid == 0) {
      ws[OFF_EDDP + (p36 * B + b) * NT + tile] = redw[0] + redw[1] + redw[2] + redw[3];
      if (diag)
        ws[OFF_TRP + (a * B + b) * NT + tile] = redw[4] + redw[5] + redw[6] + redw[7];
    }
  }
}

// ---------------------------------------------------------------------------
// k_final: assembly (sums tile partials)
__global__ __launch_bounds__(64) void k_final(
    const float* __restrict__ obs_mean, const float* __restrict__ obs_var,
    const float* __restrict__ alpha_sq, const float* __restrict__ sigma_sq_eps,
    const float* __restrict__ ws, float* __restrict__ out) {
  int b = blockIdx.x;
  int tid = threadIdx.x;
  const float* mud = ws + OFF_MUD + b * D;
  if (tid < D) out[b * D + tid] = obs_mean[b * D + tid] + mud[tid];
  if (tid < D * D) {
    int i = tid / D, j = tid % D;
    int a = i < j ? i : j;
    int dd = i < j ? j : i;
    int p36 = a * D - a * (a - 1) / 2 + (dd - a);
    float edd = 0.0f;
#pragma unroll
    for (int tt = 0; tt < NT; tt++) edd += ws[OFF_EDDP + (p36 * B + b) * NT + tt];
    float sd = edd - mud[i] * mud[j];
    if (i == j) {
      float tr = 0.0f;
#pragma unroll
      for (int tt = 0; tt < NT; tt++) tr += ws[OFF_TRP + (i * B + b) * NT + tt];
      sd += alpha_sq[i] - tr + sigma_sq_eps[i];
    }
    const float* V = ws + OFF_V;
    float cxd = V[(b * D + j) * E + i];   // C_xd[b,i,j] = V[b,j,i]
    float cdx = V[(b * D + i) * E + j];   // C_xd[b,j,i] = V[b,i,j]
    out[B * D + b * D * D + tid] = obs_var[b * D * D + tid] + sd + cxd + cdx;
  }
}

// ---------------------------------------------------------------------------
extern "C" void kernel_launch(void* const* d_in, const int* in_sizes, int n_in,
                              void* d_out, int out_size, void* d_ws, size_t ws_size,
                              hipStream_t stream) {
  const float* obs_mean     = (const float*)d_in[0];
  const float* obs_var      = (const float*)d_in[1];
  const float* action_mean  = (const float*)d_in[2];
  const float* action_var   = (const float*)d_in[3];
  const float* cross_cov    = (const float*)d_in[4];
  const float* X_train      = (const float*)d_in[5];
  const float* ell          = (const float*)d_in[6];
  const float* alpha_sq     = (const float*)d_in[7];
  const float* sigma_sq_eps = (const float*)d_in[8];
  const float* beta         = (const float*)d_in[9];
  const float* inv_K        = (const float*)d_in[10];
  float* out = (float*)d_out;
  float* ws = (float*)d_ws;

  k_prep<<<NPREP, 256, 0, stream>>>(obs_mean, obs_var, action_mean, action_var,
                                    cross_cov, X_train, ell, alpha_sq, beta, ws);
  k_q<<<NQ, 256, 0, stream>>>(obs_mean, action_mean, X_train, beta, inv_K, ws);
  k_final<<<B, 64, 0, stream>>>(obs_mean, obs_var, alpha_sq, sigma_sq_eps, ws, out);
}